// Round 14
// baseline (192.931 us; speedup 1.0000x reference)
//
#include <hip/hip_runtime.h>
#include <math.h>

// Problem constants (fixed by setup_inputs)
#define BB 8
#define NN 128
#define AA 64
#define RR 32
#define RA 16
#define PP 8128            // N*(N-1)/2 = 127*64
#define DP 32
#define HH 512
#define EE 256
#define XDIM 2560          // RR*AA + RA*DP = 2048 + 512

// workspace layout (float offsets)
static constexpr size_t WS_PAIRT = 0;                                // pair^T bf16 [b][32][8128]
static constexpr size_t WS_XB    = WS_PAIRT + (size_t)BB*DP*PP/2;    // X bf16 1024x2560
static constexpr size_t WS_EW1B  = WS_XB + (size_t)BB*NN*XDIM/2;     // ew1^T bf16 [512][2560]
static constexpr size_t WS_CW1T  = WS_EW1B + (size_t)HH*XDIM/2;      // cw1^T bf16 [128][128]
static constexpr size_t WS_CW2T  = WS_CW1T + (size_t)128*128/2;      // cw2^T bf16 [32][128]
static constexpr size_t WS_EW2B  = WS_CW2T + (size_t)DP*128/2;       // ew2^T bf16 [256][512]
static constexpr size_t WS_HB    = WS_EW2B + (size_t)EE*HH/2;        // H bf16 [1024][512]

typedef __attribute__((ext_vector_type(8))) short bf16x8;
typedef __attribute__((ext_vector_type(4))) float f32x4;

__device__ __forceinline__ float gelu_f(float x) {
    float u = 0.7978845608028654f * (x + 0.044715f * x * x * x);
    float au = fabsf(u);
    float e = __expf(-2.0f * au);
    float th = (1.0f - e) / (1.0f + e);
    th = copysignf(th, u);
    return 0.5f * x * (1.0f + th);
}

__device__ __forceinline__ unsigned short f2bf(float x) {
    union { float f; unsigned u; } v; v.f = x;
    unsigned r = v.u + 0x7fffu + ((v.u >> 16) & 1u);   // RTNE
    return (unsigned short)(r >> 16);
}

__device__ __forceinline__ bf16x8 pack_bf16x8(float4 a, float4 b) {
    bf16x8 r;
    r[0] = (short)f2bf(a.x); r[1] = (short)f2bf(a.y);
    r[2] = (short)f2bf(a.z); r[3] = (short)f2bf(a.w);
    r[4] = (short)f2bf(b.x); r[5] = (short)f2bf(b.y);
    r[6] = (short)f2bf(b.z); r[7] = (short)f2bf(b.w);
    return r;
}

// ---------------------------------------------------------------------------
// Kernel 0: prep — cw1/cw2 bf16 transposes (needed by stage1 pair path).
// grid 20: [0,16) cw1T, [16,20) cw2T
// ---------------------------------------------------------------------------
__global__ __launch_bounds__(256) void prep_k(
    const float* __restrict__ cw1, const float* __restrict__ cw2,
    unsigned short* __restrict__ cw1T, unsigned short* __restrict__ cw2T)
{
    const int bid = blockIdx.x, t = threadIdx.x;
    if (bid < 16) {
        int idx = bid * 256 + t;              // 4096
        int n = idx >> 5;
        int k0 = (idx & 31) * 4;
        ushort4 o;
        o.x = f2bf(cw1[(size_t)(k0 + 0) * 128 + n]);
        o.y = f2bf(cw1[(size_t)(k0 + 1) * 128 + n]);
        o.z = f2bf(cw1[(size_t)(k0 + 2) * 128 + n]);
        o.w = f2bf(cw1[(size_t)(k0 + 3) * 128 + n]);
        *(ushort4*)(cw1T + (size_t)n * 128 + k0) = o;
    } else {
        int idx = (bid - 16) * 256 + t;       // 1024
        int d = idx >> 5;
        int k0 = (idx & 31) * 4;
        ushort4 o;
        o.x = f2bf(cw2[(size_t)(k0 + 0) * DP + d]);
        o.y = f2bf(cw2[(size_t)(k0 + 1) * DP + d]);
        o.z = f2bf(cw2[(size_t)(k0 + 2) * DP + d]);
        o.w = f2bf(cw2[(size_t)(k0 + 3) * DP + d]);
        *(ushort4*)(cw2T + (size_t)d * 128 + k0) = o;
    }
}

// ---------------------------------------------------------------------------
// Kernel A: pair MLP (MFMA both layers) -> pairT bf16 [b][d][p]
// grid 1016 (8 b x 127 pair-tiles of 64), block 256, LDS 32KB
// ---------------------------------------------------------------------------
__global__ __launch_bounds__(256) void stage1_k(
    const float* __restrict__ afv, const unsigned short* __restrict__ cw1T,
    const float* __restrict__ cb1, const unsigned short* __restrict__ cw2T,
    const float* __restrict__ cb2, unsigned short* __restrict__ pairT)
{
    __shared__ unsigned short sm[16384];   // 32KB
    __shared__ int iis[64], jjs[64];
    const int bid = blockIdx.x;
    const int t = threadIdx.x;
    const int w = t >> 6, lane = t & 63;
    const int lm = lane & 15, lg = lane >> 4;

    const int b = bid / 127;
    const int pbase = (bid % 127) * 64;
    unsigned short* X = sm;                 // [64][128] bf16 swizzled
    unsigned short* Hs = sm + 8192;         // [64][128] bf16 swizzled

    if (t < 64) {
        int p = pbase + t;
        int i = 0;
        while (i < 126) {
            int nx = i + 1;
            int off = nx * 127 - (nx * (nx - 1)) / 2;
            if (off <= p) i = nx; else break;
        }
        int off = i * 127 - (i * (i - 1)) / 2;
        iis[t] = i;
        jjs[t] = i + 1 + (p - off);
    }
    __syncthreads();
    {
        int pp = t & 63, seg = t >> 6;
        const float* ar = afv + (size_t)(b * NN + iis[pp]) * AA + seg * 16;
        const float* br = afv + (size_t)(b * NN + jjs[pp]) * AA + seg * 16;
        float4 xa = *(const float4*)(ar),     xb2 = *(const float4*)(ar + 4);
        float4 xc = *(const float4*)(ar + 8), xd = *(const float4*)(ar + 12);
        float4 ya = *(const float4*)(br),     yb = *(const float4*)(br + 4);
        float4 yc = *(const float4*)(br + 8), yd = *(const float4*)(br + 12);
        float4 s0 = make_float4(xa.x + ya.x, xa.y + ya.y, xa.z + ya.z, xa.w + ya.w);
        float4 s1 = make_float4(xb2.x + yb.x, xb2.y + yb.y, xb2.z + yb.z, xb2.w + yb.w);
        float4 s2 = make_float4(xc.x + yc.x, xc.y + yc.y, xc.z + yc.z, xc.w + yc.w);
        float4 s3 = make_float4(xd.x + yd.x, xd.y + yd.y, xd.z + yd.z, xd.w + yd.w);
        float4 p0 = make_float4(xa.x * ya.x, xa.y * ya.y, xa.z * ya.z, xa.w * ya.w);
        float4 p1 = make_float4(xb2.x * yb.x, xb2.y * yb.y, xb2.z * yb.z, xb2.w * yb.w);
        float4 p2 = make_float4(xc.x * yc.x, xc.y * yc.y, xc.z * yc.z, xc.w * yc.w);
        float4 p3 = make_float4(xd.x * yd.x, xd.y * yd.y, xd.z * yd.z, xd.w * yd.w);
        int gs = seg * 2, gp = 8 + seg * 2, sw = pp & 7;
        *(bf16x8*)(X + pp * 128 + (((gs + 0) ^ sw) * 8)) = pack_bf16x8(s0, s1);
        *(bf16x8*)(X + pp * 128 + (((gs + 1) ^ sw) * 8)) = pack_bf16x8(s2, s3);
        *(bf16x8*)(X + pp * 128 + (((gp + 0) ^ sw) * 8)) = pack_bf16x8(p0, p1);
        *(bf16x8*)(X + pp * 128 + (((gp + 1) ^ sw) * 8)) = pack_bf16x8(p2, p3);
    }
    __syncthreads();
    const int wn = w * 32;
    f32x4 acc1[4][2];
    #pragma unroll
    for (int i = 0; i < 4; ++i)
        #pragma unroll
        for (int j = 0; j < 2; ++j) acc1[i][j] = 0.f;
    #pragma unroll
    for (int ks = 0; ks < 4; ++ks) {
        int g = ks * 4 + lg;
        bf16x8 a[4];
        #pragma unroll
        for (int mi = 0; mi < 4; ++mi) {
            int row = mi * 16 + lm;
            a[mi] = *(const bf16x8*)(X + row * 128 + ((g ^ (row & 7)) * 8));
        }
        #pragma unroll
        for (int ni = 0; ni < 2; ++ni) {
            bf16x8 bv = *(const bf16x8*)(cw1T + (size_t)(wn + ni * 16 + lm) * 128 +
                                         ks * 32 + lg * 8);
            #pragma unroll
            for (int mi = 0; mi < 4; ++mi)
                acc1[mi][ni] = __builtin_amdgcn_mfma_f32_16x16x32_bf16(
                    a[mi], bv, acc1[mi][ni], 0, 0, 0);
        }
    }
    #pragma unroll
    for (int ni = 0; ni < 2; ++ni) {
        int n = wn + ni * 16 + lm;
        float bb = cb1[n];
        int gn = n >> 3, ne = n & 7;
        #pragma unroll
        for (int mi = 0; mi < 4; ++mi)
            #pragma unroll
            for (int r = 0; r < 4; ++r) {
                int row = mi * 16 + lg * 4 + r;
                Hs[row * 128 + ((gn ^ (row & 7)) * 8 + ne)] =
                    f2bf(gelu_f(acc1[mi][ni][r] + bb));
            }
    }
    __syncthreads();
    f32x4 acc2[2];
    acc2[0] = 0.f; acc2[1] = 0.f;
    #pragma unroll
    for (int ks = 0; ks < 4; ++ks) {
        int row = w * 16 + lm;
        int g = ks * 4 + lg;
        bf16x8 a2 = *(const bf16x8*)(Hs + row * 128 + ((g ^ (row & 7)) * 8));
        #pragma unroll
        for (int ni = 0; ni < 2; ++ni) {
            bf16x8 bv = *(const bf16x8*)(cw2T + (size_t)(ni * 16 + lm) * 128 +
                                         ks * 32 + lg * 8);
            acc2[ni] = __builtin_amdgcn_mfma_f32_16x16x32_bf16(a2, bv, acc2[ni], 0, 0, 0);
        }
    }
    {
        unsigned short* T = sm;
        __syncthreads();
        #pragma unroll
        for (int ni = 0; ni < 2; ++ni) {
            int d = ni * 16 + lm;
            float bb = cb2[d];
            #pragma unroll
            for (int r = 0; r < 4; ++r) {
                int p = w * 16 + lg * 4 + r;
                T[d * 64 + p] = f2bf(acc2[ni][r] + bb);
            }
        }
        __syncthreads();
        int d = t >> 3, slot = t & 7;
        bf16x8 v = *(const bf16x8*)(T + d * 64 + slot * 8);
        *(bf16x8*)(pairT + ((size_t)b * DP + d) * PP + pbase + slot * 8) = v;
    }
}

// ---------------------------------------------------------------------------
// Kernel B (big): gav + grv + ew1/ew2 conversions + afv copy.
//   [0,256):    gav DIRECT-FRAGMENT: no LDS, no barriers.  Each wave owns
//               16 rows x 32 d; A-fragments read straight from ga (f32 ->
//               bf16 in-reg), B-fragments from L2-resident pairT.  A is
//               read exactly once from HBM; waves fully independent.
//               b = bid&7 (XCD-pinned), rt = bid>>3 (64 rows).
//   [256,768):  grv per b, 64-row tiles (LDS-staged MFMA)
//   [768,2048): ew1 -> ew1bT
//   [2048,2176): ew2 -> ew2bT
//   [2176,2240): afv copy -> out2
// ---------------------------------------------------------------------------
__global__ __launch_bounds__(256) void gav_k(
    const float* __restrict__ ga, const unsigned short* __restrict__ pairT,
    unsigned short* __restrict__ Xb,
    const float* __restrict__ gr, const float* __restrict__ afv,
    const float* __restrict__ ew1, unsigned short* __restrict__ ew1bT,
    const float* __restrict__ ew2, unsigned short* __restrict__ ew2bT,
    float* __restrict__ out2)
{
    __shared__ unsigned short sm[16384];   // 32KB (grv path only)
    const int bid = blockIdx.x;
    const int t = threadIdx.x;
    const int w = t >> 6, lane = t & 63;
    const int lm = lane & 15, lg = lane >> 4;

    if (bid >= 2176) {
        int idx = (bid - 2176) * 256 + t;   // 16384 f4
        float4 v = *(const float4*)(afv + (size_t)idx * 4);
        *(float4*)(out2 + (size_t)idx * 4) = v;
        return;
    }
    if (bid >= 2048) {
        int q = (bid - 2048) * 256 + t;     // 0..32767
        int n = q & 255;
        int k0 = (q >> 8) * 4;
        ushort4 o;
        o.x = f2bf(ew2[(size_t)(k0 + 0) * EE + n]);
        o.y = f2bf(ew2[(size_t)(k0 + 1) * EE + n]);
        o.z = f2bf(ew2[(size_t)(k0 + 2) * EE + n]);
        o.w = f2bf(ew2[(size_t)(k0 + 3) * EE + n]);
        *(ushort4*)(ew2bT + (size_t)n * HH + k0) = o;
        return;
    }
    if (bid >= 768) {
        int q = (bid - 768) * 256 + t;      // 0..327679
        int n = q & 511;
        int k0 = (q >> 9) * 4;
        ushort4 o;
        o.x = f2bf(ew1[(size_t)(k0 + 0) * HH + n]);
        o.y = f2bf(ew1[(size_t)(k0 + 1) * HH + n]);
        o.z = f2bf(ew1[(size_t)(k0 + 2) * HH + n]);
        o.w = f2bf(ew1[(size_t)(k0 + 3) * HH + n]);
        *(ushort4*)(ew1bT + (size_t)n * XDIM + k0) = o;
        return;
    }

    if (bid >= 256) {
        // ---------------- grv MFMA path, 64-row tiles (32KB LDS) ----------------
        const int gb = bid - 256;
        const int b = gb >> 6;
        const int rbase = (gb & 63) * 64;
        const float* gab = gr + ((size_t)b * 4096 + rbase) * NN;
        unsigned short* As  = sm;            // [64][128] bf16 swizzled (16KB)
        unsigned short* Bs2 = sm + 8192;     // [64][128] bf16 swizzled (16KB)
        {
            const int srow2 = t >> 2, q4 = t & 3;
            const float* arow = gab + (size_t)srow2 * NN + q4 * 32;
            #pragma unroll
            for (int j = 0; j < 4; ++j) {
                float4 x0 = *(const float4*)(arow + j * 8);
                float4 x1 = *(const float4*)(arow + j * 8 + 4);
                bf16x8 v = pack_bf16x8(x0, x1);
                int g = 4 * q4 + j;
                *(bf16x8*)(As + srow2 * 128 + ((g ^ (srow2 & 7)) * 8)) = v;
            }
        }
        #pragma unroll
        for (int q = 0; q < 8; ++q) {
            int pos = t + q * 256;           // 2048 f4: 128 m x 16 f4
            int m = pos >> 4, f4i = pos & 15;
            float4 v = *(const float4*)(afv + (size_t)(b * NN + m) * AA + f4i * 4);
            int gm = m >> 3, me = m & 7;
            float vv[4] = {v.x, v.y, v.z, v.w};
            #pragma unroll
            for (int i = 0; i < 4; ++i) {
                int a = f4i * 4 + i;
                Bs2[a * 128 + ((gm ^ (a & 7)) * 8 + me)] = f2bf(vv[i]);
            }
        }
        __syncthreads();
        const int wm = w * 16;
        f32x4 acc[4];
        #pragma unroll
        for (int j = 0; j < 4; ++j) acc[j] = 0.f;
        #pragma unroll
        for (int ks = 0; ks < 4; ++ks) {
            int g = ks * 4 + lg;
            int r0 = wm + lm;
            bf16x8 a0 = *(const bf16x8*)(As + r0 * 128 + ((g ^ (r0 & 7)) * 8));
            #pragma unroll
            for (int ni = 0; ni < 4; ++ni) {
                int a = ni * 16 + lm;
                bf16x8 bv = *(const bf16x8*)(Bs2 + a * 128 + ((g ^ (a & 7)) * 8));
                acc[ni] = __builtin_amdgcn_mfma_f32_16x16x32_bf16(a0, bv, acc[ni], 0, 0, 0);
            }
        }
        __syncthreads();
        unsigned short* T = sm;             // [64][64] bf16 (8KB)
        #pragma unroll
        for (int ni = 0; ni < 4; ++ni)
            #pragma unroll
            for (int r = 0; r < 4; ++r)
                T[(wm + lg * 4 + r) * 64 + ni * 16 + lm] = f2bf(acc[ni][r]);
        __syncthreads();
        #pragma unroll
        for (int q = 0; q < 2; ++q) {
            int idx = t + q * 256;          // 512 bf16x8 slots
            int rr2 = idx >> 3, slot = idx & 7;
            bf16x8 v = *(const bf16x8*)(T + rr2 * 64 + slot * 8);
            int grow = rbase + rr2;
            *(bf16x8*)(Xb + ((size_t)(b * NN) + (grow >> 5)) * XDIM +
                       (grow & 31) * 64 + slot * 8) = v;
        }
        return;
    }

    // ---------------- gav: direct-fragment, zero LDS, zero barriers ----------
    // block = 64 rows (4 n) x 32 d; wave w = rows rbase+w*16..+15, all 32 d.
    const int b = bid & 7, rt = bid >> 3;     // rt 0..31
    const int rbase = rt * 64;
    const int row = rbase + w * 16 + lm;      // this lane's ga row
    const float* arow_g = ga + (size_t)(b * 2048 + row) * PP;
    const unsigned short* b0row = pairT + (size_t)(b * DP + lm) * PP;       // d = lm
    const unsigned short* b1row = pairT + (size_t)(b * DP + 16 + lm) * PP;  // d = 16+lm

    f32x4 acc0 = 0.f, acc1 = 0.f;

    for (int it = 0; it < 63; ++it) {
        const int kb = it * 128;
        #pragma unroll
        for (int ks = 0; ks < 4; ++ks) {
            int k = kb + ks * 32 + lg * 8;
            float4 a0 = *(const float4*)(arow_g + k);
            float4 a1 = *(const float4*)(arow_g + k + 4);
            bf16x8 af = pack_bf16x8(a0, a1);
            bf16x8 bf0 = *(const bf16x8*)(b0row + k);
            bf16x8 bf1 = *(const bf16x8*)(b1row + k);
            acc0 = __builtin_amdgcn_mfma_f32_16x16x32_bf16(af, bf0, acc0, 0, 0, 0);
            acc1 = __builtin_amdgcn_mfma_f32_16x16x32_bf16(af, bf1, acc1, 0, 0, 0);
        }
    }
    {   // tail: k 8064..8127 (2 ks steps)
        const int kb = 8064;
        #pragma unroll
        for (int ks = 0; ks < 2; ++ks) {
            int k = kb + ks * 32 + lg * 8;
            float4 a0 = *(const float4*)(arow_g + k);
            float4 a1 = *(const float4*)(arow_g + k + 4);
            bf16x8 af = pack_bf16x8(a0, a1);
            bf16x8 bf0 = *(const bf16x8*)(b0row + k);
            bf16x8 bf1 = *(const bf16x8*)(b1row + k);
            acc0 = __builtin_amdgcn_mfma_f32_16x16x32_bf16(af, bf0, acc0, 0, 0, 0);
            acc1 = __builtin_amdgcn_mfma_f32_16x16x32_bf16(af, bf1, acc1, 0, 0, 0);
        }
    }
    // C layout: col = lane&15, row = (lane>>4)*4 + reg.  n = rt*4 + w.
    {
        const int n = rt * 4 + w;
        unsigned short* xrow = Xb + (size_t)(b * NN + n) * XDIM + 2048;
        #pragma unroll
        for (int r = 0; r < 4; ++r) {
            int a2 = lg * 4 + r;
            xrow[a2 * DP + lm]      = f2bf(acc0[r]);
            xrow[a2 * DP + 16 + lm] = f2bf(acc1[r]);
        }
    }
}

// ---------------------------------------------------------------------------
// Kernel C: mlp layer1, 32x32 tiles, grid 512, XCD-swizzled, double-buffered,
// K-tile 128 (20 iters), fused bias+gelu -> Hb bf16.  LDS 32KB.
// ---------------------------------------------------------------------------
__global__ __launch_bounds__(256) void mlp1_k(
    const unsigned short* __restrict__ Xb,
    const unsigned short* __restrict__ Wt,
    const float* __restrict__ eb1, unsigned short* __restrict__ Hb)
{
    __shared__ unsigned short sm[16384];   // 32KB: 2 x (A 8KB + B 8KB)
    const int bid = blockIdx.x;
    const int xcd = bid & 7, idx = bid >> 3;      // idx 0..63
    const int rt = (xcd << 2) | (idx & 3);        // 0..31
    const int ct = idx >> 2;                      // 0..15
    const int rbase = rt * 32, nbase = ct * 32;
    const int t = threadIdx.x;
    const int w = t >> 6, lane = t & 63;
    const int lm = lane & 15, lg = lane >> 4;
    const int wr = (w & 1) * 16, wc = (w >> 1) * 16;
    const int srow = t >> 3, sg = t & 7;

    f32x4 acc = 0.f;

    const unsigned short* Arow = Xb + (size_t)(rbase + srow) * XDIM;
    const unsigned short* Brow = Wt + (size_t)(nbase + srow) * XDIM;

    bf16x8 rA0, rA1, rB0, rB1;

#define M1_LOAD(IT)  { int kn = (IT) * 128 + sg * 8;                         \
                       rA0 = *(const bf16x8*)(Arow + kn);                    \
                       rA1 = *(const bf16x8*)(Arow + kn + 64);               \
                       rB0 = *(const bf16x8*)(Brow + kn);                    \
                       rB1 = *(const bf16x8*)(Brow + kn + 64); }
#define M1_WRITE(BUF) { unsigned short* A_ = sm + (BUF) * 8192;              \
                        unsigned short* B_ = A_ + 4096;                      \
                        int g0 = sg ^ (srow & 7);                            \
                        *(bf16x8*)(A_ + srow * 128 + g0 * 8) = rA0;          \
                        *(bf16x8*)(A_ + srow * 128 + (g0 + 8) * 8) = rA1;    \
                        *(bf16x8*)(B_ + srow * 128 + g0 * 8) = rB0;          \
                        *(bf16x8*)(B_ + srow * 128 + (g0 + 8) * 8) = rB1; }

    M1_LOAD(0); M1_WRITE(0);
    __syncthreads();
    M1_LOAD(1);

    for (int it = 0; it < 20; ++it) {
        const int cur = it & 1;
        const unsigned short* Ac = sm + cur * 8192;
        const unsigned short* Bc = Ac + 4096;
        if (it + 1 < 20) M1_WRITE(cur ^ 1);
        if (it + 2 < 20) M1_LOAD(it + 2);
        #pragma unroll
        for (int ks = 0; ks < 4; ++ks) {
            int g = ks * 4 + lg;
            int r0 = wr + lm, r1 = wc + lm;
            bf16x8 a  = *(const bf16x8*)(Ac + r0 * 128 + ((g ^ (r0 & 7)) * 8));
            bf16x8 bv = *(const bf16x8*)(Bc + r1 * 128 + ((g ^ (r1 & 7)) * 8));
            acc = __builtin_amdgcn_mfma_f32_16x16x32_bf16(a, bv, acc, 0, 0, 0);
        }
        __syncthreads();
    }
    const int col = nbase + wc + lm;
    const float bb = eb1[col];
    #pragma unroll
    for (int r = 0; r < 4; ++r) {
        int row = rbase + wr + lg * 4 + r;
        Hb[(size_t)row * HH + col] = f2bf(gelu_f(acc[r] + bb));
    }
}

// ---------------------------------------------------------------------------
// Kernel D: mlp layer2, 32x32 tiles, grid 256, XCD-swizzled, double-buffered,
// K-tile 128 (4 iters), f32 out + eb2.  LDS 32KB.
// ---------------------------------------------------------------------------
__global__ __launch_bounds__(256) void mlp2_k(
    const unsigned short* __restrict__ Hb,
    const unsigned short* __restrict__ Wt,
    const float* __restrict__ eb2, float* __restrict__ out)
{
    __shared__ unsigned short sm[16384];
    const int bid = blockIdx.x;
    const int xcd = bid & 7, idx = bid >> 3;      // idx 0..31
    const int rt = (xcd << 2) | (idx & 3);        // 0..31
    const int ct = idx >> 2;                      // 0..7
    const int rbase = rt * 32, nbase = ct * 32;
    const int t = threadIdx.x;
    const int w = t >> 6, lane = t & 63;
    const int lm = lane & 15, lg = lane >> 4;
    const int wr = (w & 1) * 16, wc = (w >> 1) * 16;
    const int srow = t >> 3, sg = t & 7;

    f32x4 acc = 0.f;

    const unsigned short* Arow = Hb + (size_t)(rbase + srow) * HH;
    const unsigned short* Brow = Wt + (size_t)(nbase + srow) * HH;

    bf16x8 rA0, rA1, rB0, rB1;

#define M2_LOAD(IT)  { int kn = (IT) * 128 + sg * 8;                         \
                       rA0 = *(const bf16x8*)(Arow + kn);                    \
                       rA1 = *(const bf16x8*)(Arow + kn + 64);               \
                       rB0 = *(const bf16x8*)(Brow + kn);                    \
                       rB1 = *(const bf16x8*)(Brow + kn + 64); }
#define M2_WRITE(BUF) { unsigned short* A_ = sm + (BUF) * 8192;              \
                        unsigned short* B_ = A_ + 4096;                      \
                        int g0 = sg ^ (srow & 7);                            \
                        *(bf16x8*)(A_ + srow * 128 + g0 * 8) = rA0;          \
                        *(bf16x8*)(A_ + srow * 128 + (g0 + 8) * 8) = rA1;    \
                        *(bf16x8*)(B_ + srow * 128 + g0 * 8) = rB0;          \
                        *(bf16x8*)(B_ + srow * 128 + (g0 + 8) * 8) = rB1; }

    M2_LOAD(0); M2_WRITE(0);
    __syncthreads();
    M2_LOAD(1);

    for (int it = 0; it < 4; ++it) {
        const int cur = it & 1;
        const unsigned short* Ac = sm + cur * 8192;
        const unsigned short* Bc = Ac + 4096;
        if (it + 1 < 4) M2_WRITE(cur ^ 1);
        if (it + 2 < 4) M2_LOAD(it + 2);
        #pragma unroll
        for (int ks = 0; ks < 4; ++ks) {
            int g = ks * 4 + lg;
            int r0 = wr + lm, r1 = wc + lm;
            bf16x8 a  = *(const bf16x8*)(Ac + r0 * 128 + ((g ^ (r0 & 7)) * 8));
            bf16x8 bv = *(const bf16x8*)(Bc + r1 * 128 + ((g ^ (r1 & 7)) * 8));
            acc = __builtin_amdgcn_mfma_f32_16x16x32_bf16(a, bv, acc, 0, 0, 0);
        }
        __syncthreads();
    }
    const int col = nbase + wc + lm;
    const float bb = eb2[col];
    #pragma unroll
    for (int r = 0; r < 4; ++r) {
        int row = rbase + wr + lg * 4 + r;
        out[(size_t)row * EE + col] = acc[r] + bb;
    }
}

extern "C" void kernel_launch(void* const* d_in, const int* in_sizes, int n_in,
                              void* d_out, int out_size, void* d_ws, size_t ws_size,
                              hipStream_t stream) {
    const float* gr  = (const float*)d_in[0];
    const float* ga  = (const float*)d_in[1];
    const float* afv = (const float*)d_in[2];
    const float* cw1 = (const float*)d_in[3];
    const float* cb1 = (const float*)d_in[4];
    const float* cw2 = (const float*)d_in[5];
    const float* cb2 = (const float*)d_in[6];
    const float* ew1 = (const float*)d_in[7];
    const float* eb1 = (const float*)d_in[8];
    const float* ew2 = (const float*)d_in[9];
    const float* eb2 = (const float*)d_in[10];
    float* out = (float*)d_out;
    float* ws = (float*)d_ws;

    unsigned short* pairT  = (unsigned short*)(ws + WS_PAIRT);
    unsigned short* Xb     = (unsigned short*)(ws + WS_XB);
    unsigned short* ew1bT  = (unsigned short*)(ws + WS_EW1B);
    unsigned short* cw1T   = (unsigned short*)(ws + WS_CW1T);
    unsigned short* cw2T   = (unsigned short*)(ws + WS_CW2T);
    unsigned short* ew2bT  = (unsigned short*)(ws + WS_EW2B);
    unsigned short* Hb     = (unsigned short*)(ws + WS_HB);

    prep_k<<<dim3(20), dim3(256), 0, stream>>>(cw1, cw2, cw1T, cw2T);
    stage1_k<<<dim3(1016), dim3(256), 0, stream>>>(afv, cw1T, cb1, cw2T, cb2, pairT);
    gav_k<<<dim3(2240), dim3(256), 0, stream>>>(ga, pairT, Xb, gr, afv,
                                                ew1, ew1bT, ew2, ew2bT,
                                                out + (size_t)BB * NN * EE);
    mlp1_k<<<dim3(512), dim3(256), 0, stream>>>(Xb, ew1bT, eb1, Hb);
    mlp2_k<<<dim3(256), dim3(256), 0, stream>>>(Hb, ew2bT, eb2, out);
}

// Round 16
// 165.828 us; speedup vs baseline: 1.1634x; 1.1634x over previous
//
#include <hip/hip_runtime.h>
#include <math.h>

// Problem constants (fixed by setup_inputs)
#define BB 8
#define NN 128
#define AA 64
#define RR 32
#define RA 16
#define PP 8128            // N*(N-1)/2 = 127*64
#define DP 32
#define HH 512
#define EE 256
#define XDIM 2560          // RR*AA + RA*DP = 2048 + 512

// workspace layout (float offsets)
static constexpr size_t WS_PAIRT = 0;                                // pair^T bf16 [b][32][8128]
static constexpr size_t WS_XB    = WS_PAIRT + (size_t)BB*DP*PP/2;    // X bf16 1024x2560
static constexpr size_t WS_EW1B  = WS_XB + (size_t)BB*NN*XDIM/2;     // ew1^T bf16 [512][2560]
static constexpr size_t WS_CW1T  = WS_EW1B + (size_t)HH*XDIM/2;      // cw1^T bf16 [128][128]
static constexpr size_t WS_CW2T  = WS_CW1T + (size_t)128*128/2;      // cw2^T bf16 [32][128]
static constexpr size_t WS_EW2B  = WS_CW2T + (size_t)DP*128/2;       // ew2^T bf16 [256][512]
static constexpr size_t WS_HB    = WS_EW2B + (size_t)EE*HH/2;        // H bf16 [1024][512]

typedef __attribute__((ext_vector_type(8))) short bf16x8;
typedef __attribute__((ext_vector_type(4))) float f32x4;

__device__ __forceinline__ float gelu_f(float x) {
    float u = 0.7978845608028654f * (x + 0.044715f * x * x * x);
    float au = fabsf(u);
    float e = __expf(-2.0f * au);
    float th = (1.0f - e) / (1.0f + e);
    th = copysignf(th, u);
    return 0.5f * x * (1.0f + th);
}

__device__ __forceinline__ unsigned short f2bf(float x) {
    union { float f; unsigned u; } v; v.f = x;
    unsigned r = v.u + 0x7fffu + ((v.u >> 16) & 1u);   // RTNE
    return (unsigned short)(r >> 16);
}

__device__ __forceinline__ bf16x8 pack_bf16x8(float4 a, float4 b) {
    bf16x8 r;
    r[0] = (short)f2bf(a.x); r[1] = (short)f2bf(a.y);
    r[2] = (short)f2bf(a.z); r[3] = (short)f2bf(a.w);
    r[4] = (short)f2bf(b.x); r[5] = (short)f2bf(b.y);
    r[6] = (short)f2bf(b.z); r[7] = (short)f2bf(b.w);
    return r;
}

// ---------------------------------------------------------------------------
// Kernel 0: prep — cw1/cw2 bf16 transposes (needed by stage1 pair path).
// grid 20: [0,16) cw1T, [16,20) cw2T
// ---------------------------------------------------------------------------
__global__ __launch_bounds__(256) void prep_k(
    const float* __restrict__ cw1, const float* __restrict__ cw2,
    unsigned short* __restrict__ cw1T, unsigned short* __restrict__ cw2T)
{
    const int bid = blockIdx.x, t = threadIdx.x;
    if (bid < 16) {
        int idx = bid * 256 + t;              // 4096
        int n = idx >> 5;
        int k0 = (idx & 31) * 4;
        ushort4 o;
        o.x = f2bf(cw1[(size_t)(k0 + 0) * 128 + n]);
        o.y = f2bf(cw1[(size_t)(k0 + 1) * 128 + n]);
        o.z = f2bf(cw1[(size_t)(k0 + 2) * 128 + n]);
        o.w = f2bf(cw1[(size_t)(k0 + 3) * 128 + n]);
        *(ushort4*)(cw1T + (size_t)n * 128 + k0) = o;
    } else {
        int idx = (bid - 16) * 256 + t;       // 1024
        int d = idx >> 5;
        int k0 = (idx & 31) * 4;
        ushort4 o;
        o.x = f2bf(cw2[(size_t)(k0 + 0) * DP + d]);
        o.y = f2bf(cw2[(size_t)(k0 + 1) * DP + d]);
        o.z = f2bf(cw2[(size_t)(k0 + 2) * DP + d]);
        o.w = f2bf(cw2[(size_t)(k0 + 3) * DP + d]);
        *(ushort4*)(cw2T + (size_t)d * 128 + k0) = o;
    }
}

// ---------------------------------------------------------------------------
// Kernel A: stage1 — pair MLP + grv + ew1/ew2 conversions + afv copy.
// (Everything that does NOT depend on pairT; overlaps freely.  gav then runs
//  alone with full machine + full HBM BW.)
//   [0,1016):     pair MLP -> pairT
//   [1016,1528):  grv per b, 64-row tiles -> Xb[...,0:2048]
//   [1528,2808):  ew1 -> ew1bT
//   [2808,2936):  ew2 -> ew2bT
//   [2936,3000):  afv copy -> out2
// block 256, LDS 32KB
// ---------------------------------------------------------------------------
__global__ __launch_bounds__(256) void stage1_k(
    const float* __restrict__ afv, const unsigned short* __restrict__ cw1T,
    const float* __restrict__ cb1, const unsigned short* __restrict__ cw2T,
    const float* __restrict__ cb2, unsigned short* __restrict__ pairT,
    const float* __restrict__ gr, unsigned short* __restrict__ Xb,
    const float* __restrict__ ew1, unsigned short* __restrict__ ew1bT,
    const float* __restrict__ ew2, unsigned short* __restrict__ ew2bT,
    float* __restrict__ out2)
{
    __shared__ unsigned short sm[16384];   // 32KB
    __shared__ int iis[64], jjs[64];
    const int bid = blockIdx.x;
    const int t = threadIdx.x;
    const int w = t >> 6, lane = t & 63;
    const int lm = lane & 15, lg = lane >> 4;

    if (bid >= 2936) {
        int idx = (bid - 2936) * 256 + t;   // 16384 f4
        float4 v = *(const float4*)(afv + (size_t)idx * 4);
        *(float4*)(out2 + (size_t)idx * 4) = v;
        return;
    }
    if (bid >= 2808) {
        int q = (bid - 2808) * 256 + t;     // 0..32767
        int n = q & 255;
        int k0 = (q >> 8) * 4;
        ushort4 o;
        o.x = f2bf(ew2[(size_t)(k0 + 0) * EE + n]);
        o.y = f2bf(ew2[(size_t)(k0 + 1) * EE + n]);
        o.z = f2bf(ew2[(size_t)(k0 + 2) * EE + n]);
        o.w = f2bf(ew2[(size_t)(k0 + 3) * EE + n]);
        *(ushort4*)(ew2bT + (size_t)n * HH + k0) = o;
        return;
    }
    if (bid >= 1528) {
        int q = (bid - 1528) * 256 + t;     // 0..327679
        int n = q & 511;
        int k0 = (q >> 9) * 4;
        ushort4 o;
        o.x = f2bf(ew1[(size_t)(k0 + 0) * HH + n]);
        o.y = f2bf(ew1[(size_t)(k0 + 1) * HH + n]);
        o.z = f2bf(ew1[(size_t)(k0 + 2) * HH + n]);
        o.w = f2bf(ew1[(size_t)(k0 + 3) * HH + n]);
        *(ushort4*)(ew1bT + (size_t)n * XDIM + k0) = o;
        return;
    }

    if (bid >= 1016) {
        // ---------------- grv MFMA path, 64-row tiles (32KB LDS) ----------------
        const int gb = bid - 1016;
        const int b = gb >> 6;
        const int rbase = (gb & 63) * 64;
        const float* gab = gr + ((size_t)b * 4096 + rbase) * NN;
        unsigned short* As  = sm;            // [64][128] bf16 swizzled (16KB)
        unsigned short* Bs2 = sm + 8192;     // [64][128] bf16 swizzled (16KB)
        {
            const int srow2 = t >> 2, q4 = t & 3;
            const float* arow = gab + (size_t)srow2 * NN + q4 * 32;
            #pragma unroll
            for (int j = 0; j < 4; ++j) {
                float4 x0 = *(const float4*)(arow + j * 8);
                float4 x1 = *(const float4*)(arow + j * 8 + 4);
                bf16x8 v = pack_bf16x8(x0, x1);
                int g = 4 * q4 + j;
                *(bf16x8*)(As + srow2 * 128 + ((g ^ (srow2 & 7)) * 8)) = v;
            }
        }
        #pragma unroll
        for (int q = 0; q < 8; ++q) {
            int pos = t + q * 256;           // 2048 f4: 128 m x 16 f4
            int m = pos >> 4, f4i = pos & 15;
            float4 v = *(const float4*)(afv + (size_t)(b * NN + m) * AA + f4i * 4);
            int gm = m >> 3, me = m & 7;
            float vv[4] = {v.x, v.y, v.z, v.w};
            #pragma unroll
            for (int i = 0; i < 4; ++i) {
                int a = f4i * 4 + i;
                Bs2[a * 128 + ((gm ^ (a & 7)) * 8 + me)] = f2bf(vv[i]);
            }
        }
        __syncthreads();
        const int wm = w * 16;
        f32x4 acc[4];
        #pragma unroll
        for (int j = 0; j < 4; ++j) acc[j] = 0.f;
        #pragma unroll
        for (int ks = 0; ks < 4; ++ks) {
            int g = ks * 4 + lg;
            int r0 = wm + lm;
            bf16x8 a0 = *(const bf16x8*)(As + r0 * 128 + ((g ^ (r0 & 7)) * 8));
            #pragma unroll
            for (int ni = 0; ni < 4; ++ni) {
                int a = ni * 16 + lm;
                bf16x8 bv = *(const bf16x8*)(Bs2 + a * 128 + ((g ^ (a & 7)) * 8));
                acc[ni] = __builtin_amdgcn_mfma_f32_16x16x32_bf16(a0, bv, acc[ni], 0, 0, 0);
            }
        }
        __syncthreads();
        unsigned short* T = sm;             // [64][64] bf16 (8KB)
        #pragma unroll
        for (int ni = 0; ni < 4; ++ni)
            #pragma unroll
            for (int r = 0; r < 4; ++r)
                T[(wm + lg * 4 + r) * 64 + ni * 16 + lm] = f2bf(acc[ni][r]);
        __syncthreads();
        #pragma unroll
        for (int q = 0; q < 2; ++q) {
            int idx = t + q * 256;          // 512 bf16x8 slots
            int rr2 = idx >> 3, slot = idx & 7;
            bf16x8 v = *(const bf16x8*)(T + rr2 * 64 + slot * 8);
            int grow = rbase + rr2;
            *(bf16x8*)(Xb + ((size_t)(b * NN) + (grow >> 5)) * XDIM +
                       (grow & 31) * 64 + slot * 8) = v;
        }
        return;
    }

    // ---------------- pair MLP MFMA path ----------------
    const int b = bid / 127;
    const int pbase = (bid % 127) * 64;
    unsigned short* X = sm;                 // [64][128] bf16 swizzled
    unsigned short* Hs = sm + 8192;         // [64][128] bf16 swizzled

    if (t < 64) {
        int p = pbase + t;
        int i = 0;
        while (i < 126) {
            int nx = i + 1;
            int off = nx * 127 - (nx * (nx - 1)) / 2;
            if (off <= p) i = nx; else break;
        }
        int off = i * 127 - (i * (i - 1)) / 2;
        iis[t] = i;
        jjs[t] = i + 1 + (p - off);
    }
    __syncthreads();
    {
        int pp = t & 63, seg = t >> 6;
        const float* ar = afv + (size_t)(b * NN + iis[pp]) * AA + seg * 16;
        const float* br = afv + (size_t)(b * NN + jjs[pp]) * AA + seg * 16;
        float4 xa = *(const float4*)(ar),     xb2 = *(const float4*)(ar + 4);
        float4 xc = *(const float4*)(ar + 8), xd = *(const float4*)(ar + 12);
        float4 ya = *(const float4*)(br),     yb = *(const float4*)(br + 4);
        float4 yc = *(const float4*)(br + 8), yd = *(const float4*)(br + 12);
        float4 s0 = make_float4(xa.x + ya.x, xa.y + ya.y, xa.z + ya.z, xa.w + ya.w);
        float4 s1 = make_float4(xb2.x + yb.x, xb2.y + yb.y, xb2.z + yb.z, xb2.w + yb.w);
        float4 s2 = make_float4(xc.x + yc.x, xc.y + yc.y, xc.z + yc.z, xc.w + yc.w);
        float4 s3 = make_float4(xd.x + yd.x, xd.y + yd.y, xd.z + yd.z, xd.w + yd.w);
        float4 p0 = make_float4(xa.x * ya.x, xa.y * ya.y, xa.z * ya.z, xa.w * ya.w);
        float4 p1 = make_float4(xb2.x * yb.x, xb2.y * yb.y, xb2.z * yb.z, xb2.w * yb.w);
        float4 p2 = make_float4(xc.x * yc.x, xc.y * yc.y, xc.z * yc.z, xc.w * yc.w);
        float4 p3 = make_float4(xd.x * yd.x, xd.y * yd.y, xd.z * yd.z, xd.w * yd.w);
        int gs = seg * 2, gp = 8 + seg * 2, sw = pp & 7;
        *(bf16x8*)(X + pp * 128 + (((gs + 0) ^ sw) * 8)) = pack_bf16x8(s0, s1);
        *(bf16x8*)(X + pp * 128 + (((gs + 1) ^ sw) * 8)) = pack_bf16x8(s2, s3);
        *(bf16x8*)(X + pp * 128 + (((gp + 0) ^ sw) * 8)) = pack_bf16x8(p0, p1);
        *(bf16x8*)(X + pp * 128 + (((gp + 1) ^ sw) * 8)) = pack_bf16x8(p2, p3);
    }
    __syncthreads();
    const int wn = w * 32;
    f32x4 acc1[4][2];
    #pragma unroll
    for (int i = 0; i < 4; ++i)
        #pragma unroll
        for (int j = 0; j < 2; ++j) acc1[i][j] = 0.f;
    #pragma unroll
    for (int ks = 0; ks < 4; ++ks) {
        int g = ks * 4 + lg;
        bf16x8 a[4];
        #pragma unroll
        for (int mi = 0; mi < 4; ++mi) {
            int row = mi * 16 + lm;
            a[mi] = *(const bf16x8*)(X + row * 128 + ((g ^ (row & 7)) * 8));
        }
        #pragma unroll
        for (int ni = 0; ni < 2; ++ni) {
            bf16x8 bv = *(const bf16x8*)(cw1T + (size_t)(wn + ni * 16 + lm) * 128 +
                                         ks * 32 + lg * 8);
            #pragma unroll
            for (int mi = 0; mi < 4; ++mi)
                acc1[mi][ni] = __builtin_amdgcn_mfma_f32_16x16x32_bf16(
                    a[mi], bv, acc1[mi][ni], 0, 0, 0);
        }
    }
    #pragma unroll
    for (int ni = 0; ni < 2; ++ni) {
        int n = wn + ni * 16 + lm;
        float bb = cb1[n];
        int gn = n >> 3, ne = n & 7;
        #pragma unroll
        for (int mi = 0; mi < 4; ++mi)
            #pragma unroll
            for (int r = 0; r < 4; ++r) {
                int row = mi * 16 + lg * 4 + r;
                Hs[row * 128 + ((gn ^ (row & 7)) * 8 + ne)] =
                    f2bf(gelu_f(acc1[mi][ni][r] + bb));
            }
    }
    __syncthreads();
    f32x4 acc2[2];
    acc2[0] = 0.f; acc2[1] = 0.f;
    #pragma unroll
    for (int ks = 0; ks < 4; ++ks) {
        int row = w * 16 + lm;
        int g = ks * 4 + lg;
        bf16x8 a2 = *(const bf16x8*)(Hs + row * 128 + ((g ^ (row & 7)) * 8));
        #pragma unroll
        for (int ni = 0; ni < 2; ++ni) {
            bf16x8 bv = *(const bf16x8*)(cw2T + (size_t)(ni * 16 + lm) * 128 +
                                         ks * 32 + lg * 8);
            acc2[ni] = __builtin_amdgcn_mfma_f32_16x16x32_bf16(a2, bv, acc2[ni], 0, 0, 0);
        }
    }
    {
        unsigned short* T = sm;
        __syncthreads();
        #pragma unroll
        for (int ni = 0; ni < 2; ++ni) {
            int d = ni * 16 + lm;
            float bb = cb2[d];
            #pragma unroll
            for (int r = 0; r < 4; ++r) {
                int p = w * 16 + lg * 4 + r;
                T[d * 64 + p] = f2bf(acc2[ni][r] + bb);
            }
        }
        __syncthreads();
        int d = t >> 3, slot = t & 7;
        bf16x8 v = *(const bf16x8*)(T + d * 64 + slot * 8);
        *(bf16x8*)(pairT + ((size_t)b * DP + d) * PP + pbase + slot * 8) = v;
    }
}

// ---------------------------------------------------------------------------
// Kernel B: gav ONLY — pure 533MB HBM stream with full machine.
// 16-row tiles, b = bid&7 (XCD-pinned), rt = bid>>3 = n.
// Double-buffered K-tile 128, 1 barrier/iter; ~4 blocks/CU.
// grid 1024, block 256.  LDS 24KB.
// ---------------------------------------------------------------------------
__global__ __launch_bounds__(256) void gav_k(
    const float* __restrict__ ga, const unsigned short* __restrict__ pairT,
    unsigned short* __restrict__ Xb)
{
    __shared__ unsigned short sm[12288];   // 24KB: 2 x (A 4KB + B 8KB)
    const int bid = blockIdx.x;
    const int t = threadIdx.x;
    const int w = t >> 6, lane = t & 63;
    const int lm = lane & 15, lg = lane >> 4;

    const int b = bid & 7, rt = bid >> 3;     // rt = n (0..127)
    const int rbase = rt * 16;
    const int srow = t >> 4, slot = t & 15;   // A staging: 16 rows x 16 k-slots
    const int bd = t >> 3, bslot = t & 7;     // B staging: 32 d x 8 slots (x2 halves)
    const int wc = w * 16;                    // waves 0,1 compute; 2,3 stage-only

    f32x4 acc = 0.f;

    const float* gab = ga + (size_t)(b * 2048 + rbase) * PP;
    const unsigned short* pbT = pairT + (size_t)b * DP * PP;

    float4 ra0, ra1;
    bf16x8 rb0, rb1;

#define GAV_LOAD(IT)                                                         \
    {                                                                        \
        int kn = (IT) * 128 + slot * 8;                                      \
        if (kn > PP - 8) kn = PP - 8;          /* tail clamp (junk unread) */ \
        ra0 = *(const float4*)(gab + (size_t)srow * PP + kn);                \
        ra1 = *(const float4*)(gab + (size_t)srow * PP + kn + 4);            \
        int kb = (IT) * 128 + bslot * 8;                                     \
        int kb1 = kb + 64; if (kb1 > PP - 8) kb1 = PP - 8;                   \
        rb0 = *(const bf16x8*)(pbT + (size_t)bd * PP + kb);                  \
        rb1 = *(const bf16x8*)(pbT + (size_t)bd * PP + kb1);                 \
    }

#define GAV_WRITE(BUF)                                                      \
    {                                                                        \
        unsigned short* A_ = sm + (BUF) * 6144;                              \
        unsigned short* B_ = A_ + 2048;                                      \
        int gA = slot ^ (srow & 7);                                          \
        *(bf16x8*)(A_ + srow * 128 + gA * 8) = pack_bf16x8(ra0, ra1);        \
        int gB = bslot ^ (bd & 7);                                           \
        *(bf16x8*)(B_ + bd * 128 + gB * 8) = rb0;                            \
        *(bf16x8*)(B_ + bd * 128 + (gB + 8) * 8) = rb1;                      \
    }

    GAV_LOAD(0);
    GAV_WRITE(0);
    __syncthreads();
    GAV_LOAD(1);

    for (int it = 0; it < 64; ++it) {
        const int cur = it & 1;
        const unsigned short* Ac = sm + cur * 6144;
        const unsigned short* Bc = Ac + 2048;
        if (it + 1 < 64) GAV_WRITE(cur ^ 1);
        if (it + 2 < 64) GAV_LOAD(it + 2);
        if (w < 2) {
            const int nk = (it < 63) ? 4 : 2;    // tail: only k 8064..8127 valid
            for (int ks = 0; ks < nk; ++ks) {
                int gg = ks * 4 + lg;
                int rowb = wc + lm;
                bf16x8 a  = *(const bf16x8*)(Ac + lm * 128 + ((gg ^ (lm & 7)) * 8));
                bf16x8 bv = *(const bf16x8*)(Bc + rowb * 128 + ((gg ^ (rowb & 7)) * 8));
                acc = __builtin_amdgcn_mfma_f32_16x16x32_bf16(a, bv, acc, 0, 0, 0);
            }
        }
        __syncthreads();
    }
    // C layout: col = lane&15, row = (lane>>4)*4 + reg.  Block = one n (=rt).
    if (w < 2) {
        #pragma unroll
        for (int r = 0; r < 4; ++r) {
            int a2 = lg * 4 + r;
            Xb[(size_t)(b * NN + rt) * XDIM + 2048 + a2 * DP + wc + lm] = f2bf(acc[r]);
        }
    }
}

// ---------------------------------------------------------------------------
// Kernel C: mlp layer1, 32x32 tiles, grid 512, XCD-swizzled, double-buffered,
// K-tile 128 (20 iters), fused bias+gelu -> Hb bf16.  LDS 32KB.
// ---------------------------------------------------------------------------
__global__ __launch_bounds__(256) void mlp1_k(
    const unsigned short* __restrict__ Xb,
    const unsigned short* __restrict__ Wt,
    const float* __restrict__ eb1, unsigned short* __restrict__ Hb)
{
    __shared__ unsigned short sm[16384];   // 32KB: 2 x (A 8KB + B 8KB)
    const int bid = blockIdx.x;
    const int xcd = bid & 7, idx = bid >> 3;      // idx 0..63
    const int rt = (xcd << 2) | (idx & 3);        // 0..31
    const int ct = idx >> 2;                      // 0..15
    const int rbase = rt * 32, nbase = ct * 32;
    const int t = threadIdx.x;
    const int w = t >> 6, lane = t & 63;
    const int lm = lane & 15, lg = lane >> 4;
    const int wr = (w & 1) * 16, wc = (w >> 1) * 16;
    const int srow = t >> 3, sg = t & 7;

    f32x4 acc = 0.f;

    const unsigned short* Arow = Xb + (size_t)(rbase + srow) * XDIM;
    const unsigned short* Brow = Wt + (size_t)(nbase + srow) * XDIM;

    bf16x8 rA0, rA1, rB0, rB1;

#define M1_LOAD(IT)  { int kn = (IT) * 128 + sg * 8;                         \
                       rA0 = *(const bf16x8*)(Arow + kn);                    \
                       rA1 = *(const bf16x8*)(Arow + kn + 64);               \
                       rB0 = *(const bf16x8*)(Brow + kn);                    \
                       rB1 = *(const bf16x8*)(Brow + kn + 64); }
#define M1_WRITE(BUF) { unsigned short* A_ = sm + (BUF) * 8192;              \
                        unsigned short* B_ = A_ + 4096;                      \
                        int g0 = sg ^ (srow & 7);                            \
                        *(bf16x8*)(A_ + srow * 128 + g0 * 8) = rA0;          \
                        *(bf16x8*)(A_ + srow * 128 + (g0 + 8) * 8) = rA1;    \
                        *(bf16x8*)(B_ + srow * 128 + g0 * 8) = rB0;          \
                        *(bf16x8*)(B_ + srow * 128 + (g0 + 8) * 8) = rB1; }

    M1_LOAD(0); M1_WRITE(0);
    __syncthreads();
    M1_LOAD(1);

    for (int it = 0; it < 20; ++it) {
        const int cur = it & 1;
        const unsigned short* Ac = sm + cur * 8192;
        const unsigned short* Bc = Ac + 4096;
        if (it + 1 < 20) M1_WRITE(cur ^ 1);
        if (it + 2 < 20) M1_LOAD(it + 2);
        #pragma unroll
        for (int ks = 0; ks < 4; ++ks) {
            int g = ks * 4 + lg;
            int r0 = wr + lm, r1 = wc + lm;
            bf16x8 a  = *(const bf16x8*)(Ac + r0 * 128 + ((g ^ (r0 & 7)) * 8));
            bf16x8 bv = *(const bf16x8*)(Bc + r1 * 128 + ((g ^ (r1 & 7)) * 8));
            acc = __builtin_amdgcn_mfma_f32_16x16x32_bf16(a, bv, acc, 0, 0, 0);
        }
        __syncthreads();
    }
    const int col = nbase + wc + lm;
    const float bb = eb1[col];
    #pragma unroll
    for (int r = 0; r < 4; ++r) {
        int row = rbase + wr + lg * 4 + r;
        Hb[(size_t)row * HH + col] = f2bf(gelu_f(acc[r] + bb));
    }
}

// ---------------------------------------------------------------------------
// Kernel D: mlp layer2, 32x32 tiles, grid 256, XCD-swizzled, double-buffered,
// K-tile 128 (4 iters), f32 out + eb2.  LDS 32KB.
// ---------------------------------------------------------------------------
__global__ __launch_bounds__(256) void mlp2_k(
    const unsigned short* __restrict__ Hb,
    const unsigned short* __restrict__ Wt,
    const float* __restrict__ eb2, float* __restrict__ out)
{
    __shared__ unsigned short sm[16384];
    const int bid = blockIdx.x;
    const int xcd = bid & 7, idx = bid >> 3;      // idx 0..31
    const int rt = (xcd << 2) | (idx & 3);        // 0..31
    const int ct = idx >> 2;                      // 0..7
    const int rbase = rt * 32, nbase = ct * 32;
    const int t = threadIdx.x;
    const int w = t >> 6, lane = t & 63;
    const int lm = lane & 15, lg = lane >> 4;
    const int wr = (w & 1) * 16, wc = (w >> 1) * 16;
    const int srow = t >> 3, sg = t & 7;

    f32x4 acc = 0.f;

    const unsigned short* Arow = Hb + (size_t)(rbase + srow) * HH;
    const unsigned short* Brow = Wt + (size_t)(nbase + srow) * HH;

    bf16x8 rA0, rA1, rB0, rB1;

#define M2_LOAD(IT)  { int kn = (IT) * 128 + sg * 8;                         \
                       rA0 = *(const bf16x8*)(Arow + kn);                    \
                       rA1 = *(const bf16x8*)(Arow + kn + 64);               \
                       rB0 = *(const bf16x8*)(Brow + kn);                    \
                       rB1 = *(const bf16x8*)(Brow + kn + 64); }
#define M2_WRITE(BUF) { unsigned short* A_ = sm + (BUF) * 8192;              \
                        unsigned short* B_ = A_ + 4096;                      \
                        int g0 = sg ^ (srow & 7);                            \
                        *(bf16x8*)(A_ + srow * 128 + g0 * 8) = rA0;          \
                        *(bf16x8*)(A_ + srow * 128 + (g0 + 8) * 8) = rA1;    \
                        *(bf16x8*)(B_ + srow * 128 + g0 * 8) = rB0;          \
                        *(bf16x8*)(B_ + srow * 128 + (g0 + 8) * 8) = rB1; }

    M2_LOAD(0); M2_WRITE(0);
    __syncthreads();
    M2_LOAD(1);

    for (int it = 0; it < 4; ++it) {
        const int cur = it & 1;
        const unsigned short* Ac = sm + cur * 8192;
        const unsigned short* Bc = Ac + 4096;
        if (it + 1 < 4) M2_WRITE(cur ^ 1);
        if (it + 2 < 4) M2_LOAD(it + 2);
        #pragma unroll
        for (int ks = 0; ks < 4; ++ks) {
            int g = ks * 4 + lg;
            int r0 = wr + lm, r1 = wc + lm;
            bf16x8 a  = *(const bf16x8*)(Ac + r0 * 128 + ((g ^ (r0 & 7)) * 8));
            bf16x8 bv = *(const bf16x8*)(Bc + r1 * 128 + ((g ^ (r1 & 7)) * 8));
            acc = __builtin_amdgcn_mfma_f32_16x16x32_bf16(a, bv, acc, 0, 0, 0);
        }
        __syncthreads();
    }
    const int col = nbase + wc + lm;
    const float bb = eb2[col];
    #pragma unroll
    for (int r = 0; r < 4; ++r) {
        int row = rbase + wr + lg * 4 + r;
        out[(size_t)row * EE + col] = acc[r] + bb;
    }
}

extern "C" void kernel_launch(void* const* d_in, const int* in_sizes, int n_in,
                              void* d_out, int out_size, void* d_ws, size_t ws_size,
                              hipStream_t stream) {
    const float* gr  = (const float*)d_in[0];
    const float* ga  = (const float*)d_in[1];
    const float* afv = (const float*)d_in[2];
    const float* cw1 = (const float*)d_in[3];
    const float* cb1 = (const float*)d_in[4];
    const float* cw2 = (const float*)d_in[5];
    const float* cb2 = (const float*)d_in[6];
    const float* ew1 = (const float*)d_in[7];
    const float* eb1 = (const float*)d_in[8];
    const float* ew2 = (const float*)d_in[9];
    const float* eb2 = (const float*)d_in[10];
    float* out = (float*)d_out;
    float* ws = (float*)d_ws;

    unsigned short* pairT  = (unsigned short*)(ws + WS_PAIRT);
    unsigned short* Xb     = (unsigned short*)(ws + WS_XB);
    unsigned short* ew1bT  = (unsigned short*)(ws + WS_EW1B);
    unsigned short* cw1T   = (unsigned short*)(ws + WS_CW1T);
    unsigned short* cw2T   = (unsigned short*)(ws + WS_CW2T);
    unsigned short* ew2bT  = (unsigned short*)(ws + WS_EW2B);
    unsigned short* Hb     = (unsigned short*)(ws + WS_HB);

    prep_k<<<dim3(20), dim3(256), 0, stream>>>(cw1, cw2, cw1T, cw2T);
    stage1_k<<<dim3(3000), dim3(256), 0, stream>>>(afv, cw1T, cb1, cw2T, cb2, pairT,
                                                   gr, Xb, ew1, ew1bT, ew2, ew2bT,
                                                   out + (size_t)BB * NN * EE);
    gav_k<<<dim3(1024), dim3(256), 0, stream>>>(ga, pairT, Xb);
    mlp1_k<<<dim3(512), dim3(256), 0, stream>>>(Xb, ew1bT, eb1, Hb);
    mlp2_k<<<dim3(256), dim3(256), 0, stream>>>(Hb, ew2bT, eb2, out);
}

// Round 17
// 162.734 us; speedup vs baseline: 1.1856x; 1.0190x over previous
//
#include <hip/hip_runtime.h>
#include <math.h>

// Problem constants (fixed by setup_inputs)
#define BB 8
#define NN 128
#define AA 64
#define RR 32
#define RA 16
#define PP 8128            // N*(N-1)/2 = 127*64
#define DP 32
#define HH 512
#define EE 256
#define XDIM 2560          // RR*AA + RA*DP = 2048 + 512

// workspace layout (float offsets)
static constexpr size_t WS_PAIRT = 0;                                // pair^T bf16 [b][32][8128]
static constexpr size_t WS_XB    = WS_PAIRT + (size_t)BB*DP*PP/2;    // X bf16 1024x2560
static constexpr size_t WS_EW1B  = WS_XB + (size_t)BB*NN*XDIM/2;     // ew1^T bf16 [512][2560]
static constexpr size_t WS_CW1T  = WS_EW1B + (size_t)HH*XDIM/2;      // cw1^T bf16 [128][128]
static constexpr size_t WS_CW2T  = WS_CW1T + (size_t)128*128/2;      // cw2^T bf16 [32][128]
static constexpr size_t WS_EW2B  = WS_CW2T + (size_t)DP*128/2;       // ew2^T bf16 [256][512]
static constexpr size_t WS_HB    = WS_EW2B + (size_t)EE*HH/2;        // H bf16 [1024][512]

typedef __attribute__((ext_vector_type(8))) short bf16x8;
typedef __attribute__((ext_vector_type(4))) float f32x4;

__device__ __forceinline__ float gelu_f(float x) {
    float u = 0.7978845608028654f * (x + 0.044715f * x * x * x);
    float au = fabsf(u);
    float e = __expf(-2.0f * au);
    float th = (1.0f - e) / (1.0f + e);
    th = copysignf(th, u);
    return 0.5f * x * (1.0f + th);
}

__device__ __forceinline__ unsigned short f2bf(float x) {
    union { float f; unsigned u; } v; v.f = x;
    unsigned r = v.u + 0x7fffu + ((v.u >> 16) & 1u);   // RTNE
    return (unsigned short)(r >> 16);
}

__device__ __forceinline__ bf16x8 pack_bf16x8(float4 a, float4 b) {
    bf16x8 r;
    r[0] = (short)f2bf(a.x); r[1] = (short)f2bf(a.y);
    r[2] = (short)f2bf(a.z); r[3] = (short)f2bf(a.w);
    r[4] = (short)f2bf(b.x); r[5] = (short)f2bf(b.y);
    r[6] = (short)f2bf(b.z); r[7] = (short)f2bf(b.w);
    return r;
}

// ---------------------------------------------------------------------------
// Kernel 0: prep — cw1/cw2 bf16 transposes (needed by stage1 pair path).
// grid 20: [0,16) cw1T, [16,20) cw2T
// ---------------------------------------------------------------------------
__global__ __launch_bounds__(256) void prep_k(
    const float* __restrict__ cw1, const float* __restrict__ cw2,
    unsigned short* __restrict__ cw1T, unsigned short* __restrict__ cw2T)
{
    const int bid = blockIdx.x, t = threadIdx.x;
    if (bid < 16) {
        int idx = bid * 256 + t;              // 4096
        int n = idx >> 5;
        int k0 = (idx & 31) * 4;
        ushort4 o;
        o.x = f2bf(cw1[(size_t)(k0 + 0) * 128 + n]);
        o.y = f2bf(cw1[(size_t)(k0 + 1) * 128 + n]);
        o.z = f2bf(cw1[(size_t)(k0 + 2) * 128 + n]);
        o.w = f2bf(cw1[(size_t)(k0 + 3) * 128 + n]);
        *(ushort4*)(cw1T + (size_t)n * 128 + k0) = o;
    } else {
        int idx = (bid - 16) * 256 + t;       // 1024
        int d = idx >> 5;
        int k0 = (idx & 31) * 4;
        ushort4 o;
        o.x = f2bf(cw2[(size_t)(k0 + 0) * DP + d]);
        o.y = f2bf(cw2[(size_t)(k0 + 1) * DP + d]);
        o.z = f2bf(cw2[(size_t)(k0 + 2) * DP + d]);
        o.w = f2bf(cw2[(size_t)(k0 + 3) * DP + d]);
        *(ushort4*)(cw2T + (size_t)d * 128 + k0) = o;
    }
}

// ---------------------------------------------------------------------------
// Kernel A: pair MLP (MFMA both layers) -> pairT bf16 [b][d][p]
// grid 1016 (8 b x 127 pair-tiles of 64), block 256, LDS 32KB
// ---------------------------------------------------------------------------
__global__ __launch_bounds__(256) void stage1_k(
    const float* __restrict__ afv, const unsigned short* __restrict__ cw1T,
    const float* __restrict__ cb1, const unsigned short* __restrict__ cw2T,
    const float* __restrict__ cb2, unsigned short* __restrict__ pairT)
{
    __shared__ unsigned short sm[16384];   // 32KB
    __shared__ int iis[64], jjs[64];
    const int bid = blockIdx.x;
    const int t = threadIdx.x;
    const int w = t >> 6, lane = t & 63;
    const int lm = lane & 15, lg = lane >> 4;

    const int b = bid / 127;
    const int pbase = (bid % 127) * 64;
    unsigned short* X = sm;                 // [64][128] bf16 swizzled
    unsigned short* Hs = sm + 8192;         // [64][128] bf16 swizzled

    if (t < 64) {
        int p = pbase + t;
        int i = 0;
        while (i < 126) {
            int nx = i + 1;
            int off = nx * 127 - (nx * (nx - 1)) / 2;
            if (off <= p) i = nx; else break;
        }
        int off = i * 127 - (i * (i - 1)) / 2;
        iis[t] = i;
        jjs[t] = i + 1 + (p - off);
    }
    __syncthreads();
    {
        int pp = t & 63, seg = t >> 6;
        const float* ar = afv + (size_t)(b * NN + iis[pp]) * AA + seg * 16;
        const float* br = afv + (size_t)(b * NN + jjs[pp]) * AA + seg * 16;
        float4 xa = *(const float4*)(ar),     xb2 = *(const float4*)(ar + 4);
        float4 xc = *(const float4*)(ar + 8), xd = *(const float4*)(ar + 12);
        float4 ya = *(const float4*)(br),     yb = *(const float4*)(br + 4);
        float4 yc = *(const float4*)(br + 8), yd = *(const float4*)(br + 12);
        float4 s0 = make_float4(xa.x + ya.x, xa.y + ya.y, xa.z + ya.z, xa.w + ya.w);
        float4 s1 = make_float4(xb2.x + yb.x, xb2.y + yb.y, xb2.z + yb.z, xb2.w + yb.w);
        float4 s2 = make_float4(xc.x + yc.x, xc.y + yc.y, xc.z + yc.z, xc.w + yc.w);
        float4 s3 = make_float4(xd.x + yd.x, xd.y + yd.y, xd.z + yd.z, xd.w + yd.w);
        float4 p0 = make_float4(xa.x * ya.x, xa.y * ya.y, xa.z * ya.z, xa.w * ya.w);
        float4 p1 = make_float4(xb2.x * yb.x, xb2.y * yb.y, xb2.z * yb.z, xb2.w * yb.w);
        float4 p2 = make_float4(xc.x * yc.x, xc.y * yc.y, xc.z * yc.z, xc.w * yc.w);
        float4 p3 = make_float4(xd.x * yd.x, xd.y * yd.y, xd.z * yd.z, xd.w * yd.w);
        int gs = seg * 2, gp = 8 + seg * 2, sw = pp & 7;
        *(bf16x8*)(X + pp * 128 + (((gs + 0) ^ sw) * 8)) = pack_bf16x8(s0, s1);
        *(bf16x8*)(X + pp * 128 + (((gs + 1) ^ sw) * 8)) = pack_bf16x8(s2, s3);
        *(bf16x8*)(X + pp * 128 + (((gp + 0) ^ sw) * 8)) = pack_bf16x8(p0, p1);
        *(bf16x8*)(X + pp * 128 + (((gp + 1) ^ sw) * 8)) = pack_bf16x8(p2, p3);
    }
    __syncthreads();
    const int wn = w * 32;
    f32x4 acc1[4][2];
    #pragma unroll
    for (int i = 0; i < 4; ++i)
        #pragma unroll
        for (int j = 0; j < 2; ++j) acc1[i][j] = 0.f;
    #pragma unroll
    for (int ks = 0; ks < 4; ++ks) {
        int g = ks * 4 + lg;
        bf16x8 a[4];
        #pragma unroll
        for (int mi = 0; mi < 4; ++mi) {
            int row = mi * 16 + lm;
            a[mi] = *(const bf16x8*)(X + row * 128 + ((g ^ (row & 7)) * 8));
        }
        #pragma unroll
        for (int ni = 0; ni < 2; ++ni) {
            bf16x8 bv = *(const bf16x8*)(cw1T + (size_t)(wn + ni * 16 + lm) * 128 +
                                         ks * 32 + lg * 8);
            #pragma unroll
            for (int mi = 0; mi < 4; ++mi)
                acc1[mi][ni] = __builtin_amdgcn_mfma_f32_16x16x32_bf16(
                    a[mi], bv, acc1[mi][ni], 0, 0, 0);
        }
    }
    #pragma unroll
    for (int ni = 0; ni < 2; ++ni) {
        int n = wn + ni * 16 + lm;
        float bb = cb1[n];
        int gn = n >> 3, ne = n & 7;
        #pragma unroll
        for (int mi = 0; mi < 4; ++mi)
            #pragma unroll
            for (int r = 0; r < 4; ++r) {
                int row = mi * 16 + lg * 4 + r;
                Hs[row * 128 + ((gn ^ (row & 7)) * 8 + ne)] =
                    f2bf(gelu_f(acc1[mi][ni][r] + bb));
            }
    }
    __syncthreads();
    f32x4 acc2[2];
    acc2[0] = 0.f; acc2[1] = 0.f;
    #pragma unroll
    for (int ks = 0; ks < 4; ++ks) {
        int row = w * 16 + lm;
        int g = ks * 4 + lg;
        bf16x8 a2 = *(const bf16x8*)(Hs + row * 128 + ((g ^ (row & 7)) * 8));
        #pragma unroll
        for (int ni = 0; ni < 2; ++ni) {
            bf16x8 bv = *(const bf16x8*)(cw2T + (size_t)(ni * 16 + lm) * 128 +
                                         ks * 32 + lg * 8);
            acc2[ni] = __builtin_amdgcn_mfma_f32_16x16x32_bf16(a2, bv, acc2[ni], 0, 0, 0);
        }
    }
    {
        unsigned short* T = sm;
        __syncthreads();
        #pragma unroll
        for (int ni = 0; ni < 2; ++ni) {
            int d = ni * 16 + lm;
            float bb = cb2[d];
            #pragma unroll
            for (int r = 0; r < 4; ++r) {
                int p = w * 16 + lg * 4 + r;
                T[d * 64 + p] = f2bf(acc2[ni][r] + bb);
            }
        }
        __syncthreads();
        int d = t >> 3, slot = t & 7;
        bf16x8 v = *(const bf16x8*)(T + d * 64 + slot * 8);
        *(bf16x8*)(pairT + ((size_t)b * DP + d) * PP + pbase + slot * 8) = v;
    }
}

// ---------------------------------------------------------------------------
// Kernel B (big): gav + grv + ew1/ew2 conversions + afv copy.  LDS 32KB.
//   [0,1024):    gav 16-row tiles, b = bid&7 (XCD-pinned), rt = bid>>3 = n.
//                Double-buffered K-tile 128; ~4 blocks/CU.
//   [1024,1536): grv per b, 64-row tiles (self-staged afv transpose in LDS)
//   [1536,2816): ew1 -> ew1bT
//   [2816,2944): ew2 -> ew2bT
//   [2944,3008): afv copy -> out2
// ---------------------------------------------------------------------------
__global__ __launch_bounds__(256) void gav_k(
    const float* __restrict__ ga, const unsigned short* __restrict__ pairT,
    unsigned short* __restrict__ Xb,
    const float* __restrict__ gr, const float* __restrict__ afv,
    const float* __restrict__ ew1, unsigned short* __restrict__ ew1bT,
    const float* __restrict__ ew2, unsigned short* __restrict__ ew2bT,
    float* __restrict__ out2)
{
    __shared__ unsigned short sm[16384];   // 32KB multi-purpose
    const int bid = blockIdx.x;
    const int t = threadIdx.x;
    const int w = t >> 6, lane = t & 63;
    const int lm = lane & 15, lg = lane >> 4;

    if (bid >= 2944) {
        int idx = (bid - 2944) * 256 + t;   // 16384 f4
        float4 v = *(const float4*)(afv + (size_t)idx * 4);
        *(float4*)(out2 + (size_t)idx * 4) = v;
        return;
    }
    if (bid >= 2816) {
        int q = (bid - 2816) * 256 + t;     // 0..32767
        int n = q & 255;
        int k0 = (q >> 8) * 4;
        ushort4 o;
        o.x = f2bf(ew2[(size_t)(k0 + 0) * EE + n]);
        o.y = f2bf(ew2[(size_t)(k0 + 1) * EE + n]);
        o.z = f2bf(ew2[(size_t)(k0 + 2) * EE + n]);
        o.w = f2bf(ew2[(size_t)(k0 + 3) * EE + n]);
        *(ushort4*)(ew2bT + (size_t)n * HH + k0) = o;
        return;
    }
    if (bid >= 1536) {
        int q = (bid - 1536) * 256 + t;     // 0..327679
        int n = q & 511;
        int k0 = (q >> 9) * 4;
        ushort4 o;
        o.x = f2bf(ew1[(size_t)(k0 + 0) * HH + n]);
        o.y = f2bf(ew1[(size_t)(k0 + 1) * HH + n]);
        o.z = f2bf(ew1[(size_t)(k0 + 2) * HH + n]);
        o.w = f2bf(ew1[(size_t)(k0 + 3) * HH + n]);
        *(ushort4*)(ew1bT + (size_t)n * XDIM + k0) = o;
        return;
    }

    if (bid >= 1024) {
        // ---------------- grv MFMA path, 64-row tiles (32KB LDS) ----------------
        const int gb = bid - 1024;
        const int b = gb >> 6;
        const int rbase = (gb & 63) * 64;
        const float* gab = gr + ((size_t)b * 4096 + rbase) * NN;
        unsigned short* As  = sm;            // [64][128] bf16 swizzled (16KB)
        unsigned short* Bs2 = sm + 8192;     // [64][128] bf16 swizzled (16KB)
        // stage gr f32 -> bf16 LDS: thread (srow2 = t>>2, q4 = t&3) covers k q4*32..+31
        {
            const int srow2 = t >> 2, q4 = t & 3;
            const float* arow = gab + (size_t)srow2 * NN + q4 * 32;
            #pragma unroll
            for (int j = 0; j < 4; ++j) {
                float4 x0 = *(const float4*)(arow + j * 8);
                float4 x1 = *(const float4*)(arow + j * 8 + 4);
                bf16x8 v = pack_bf16x8(x0, x1);
                int g = 4 * q4 + j;
                *(bf16x8*)(As + srow2 * 128 + ((g ^ (srow2 & 7)) * 8)) = v;
            }
        }
        // stage afv[b] transposed: Bs2[a][m]
        #pragma unroll
        for (int q = 0; q < 8; ++q) {
            int pos = t + q * 256;           // 2048 f4: 128 m x 16 f4
            int m = pos >> 4, f4i = pos & 15;
            float4 v = *(const float4*)(afv + (size_t)(b * NN + m) * AA + f4i * 4);
            int gm = m >> 3, me = m & 7;
            float vv[4] = {v.x, v.y, v.z, v.w};
            #pragma unroll
            for (int i = 0; i < 4; ++i) {
                int a = f4i * 4 + i;
                Bs2[a * 128 + ((gm ^ (a & 7)) * 8 + me)] = f2bf(vv[i]);
            }
        }
        __syncthreads();
        const int wm = w * 16;
        f32x4 acc[4];
        #pragma unroll
        for (int j = 0; j < 4; ++j) acc[j] = 0.f;
        #pragma unroll
        for (int ks = 0; ks < 4; ++ks) {
            int g = ks * 4 + lg;
            int r0 = wm + lm;
            bf16x8 a0 = *(const bf16x8*)(As + r0 * 128 + ((g ^ (r0 & 7)) * 8));
            #pragma unroll
            for (int ni = 0; ni < 4; ++ni) {
                int a = ni * 16 + lm;
                bf16x8 bv = *(const bf16x8*)(Bs2 + a * 128 + ((g ^ (a & 7)) * 8));
                acc[ni] = __builtin_amdgcn_mfma_f32_16x16x32_bf16(a0, bv, acc[ni], 0, 0, 0);
            }
        }
        __syncthreads();
        unsigned short* T = sm;             // [64][64] bf16 (8KB)
        #pragma unroll
        for (int ni = 0; ni < 4; ++ni)
            #pragma unroll
            for (int r = 0; r < 4; ++r)
                T[(wm + lg * 4 + r) * 64 + ni * 16 + lm] = f2bf(acc[ni][r]);
        __syncthreads();
        #pragma unroll
        for (int q = 0; q < 2; ++q) {
            int idx = t + q * 256;          // 512 bf16x8 slots
            int rr2 = idx >> 3, slot = idx & 7;
            bf16x8 v = *(const bf16x8*)(T + rr2 * 64 + slot * 8);
            int grow = rbase + rr2;
            *(bf16x8*)(Xb + ((size_t)(b * NN) + (grow >> 5)) * XDIM +
                       (grow & 31) * 64 + slot * 8) = v;
        }
        return;
    }

    // ---------------- gav (XCD-pinned by b, 16-row tiles, double-buffered) ----
    const int b = bid & 7, rt = bid >> 3;     // rt = n (0..127)
    const int rbase = rt * 16;
    const int srow = t >> 4, slot = t & 15;   // A staging: 16 rows x 16 k-slots
    const int bd = t >> 3, bslot = t & 7;     // B staging: 32 d x 8 slots (x2 halves)
    const int wc = w * 16;                    // waves 0,1 compute; 2,3 stage-only

    f32x4 acc = 0.f;

    const float* gab = ga + (size_t)(b * 2048 + rbase) * PP;
    const unsigned short* pbT = pairT + (size_t)b * DP * PP;

    float4 ra0, ra1;
    bf16x8 rb0, rb1;

#define GAV_LOAD(IT)                                                         \
    {                                                                        \
        int kn = (IT) * 128 + slot * 8;                                      \
        if (kn > PP - 8) kn = PP - 8;          /* tail clamp (junk unread) */ \
        ra0 = *(const float4*)(gab + (size_t)srow * PP + kn);                \
        ra1 = *(const float4*)(gab + (size_t)srow * PP + kn + 4);            \
        int kb = (IT) * 128 + bslot * 8;                                     \
        int kb1 = kb + 64; if (kb1 > PP - 8) kb1 = PP - 8;                   \
        rb0 = *(const bf16x8*)(pbT + (size_t)bd * PP + kb);                  \
        rb1 = *(const bf16x8*)(pbT + (size_t)bd * PP + kb1);                 \
    }

#define GAV_WRITE(BUF)                                                      \
    {                                                                        \
        unsigned short* A_ = sm + (BUF) * 6144;                              \
        unsigned short* B_ = A_ + 2048;                                      \
        int gA = slot ^ (srow & 7);                                          \
        *(bf16x8*)(A_ + srow * 128 + gA * 8) = pack_bf16x8(ra0, ra1);        \
        int gB = bslot ^ (bd & 7);                                           \
        *(bf16x8*)(B_ + bd * 128 + gB * 8) = rb0;                            \
        *(bf16x8*)(B_ + bd * 128 + (gB + 8) * 8) = rb1;                      \
    }

    GAV_LOAD(0);
    GAV_WRITE(0);
    __syncthreads();
    GAV_LOAD(1);

    for (int it = 0; it < 64; ++it) {
        const int cur = it & 1;
        const unsigned short* Ac = sm + cur * 6144;
        const unsigned short* Bc = Ac + 2048;
        if (it + 1 < 64) GAV_WRITE(cur ^ 1);
        if (it + 2 < 64) GAV_LOAD(it + 2);
        if (w < 2) {
            const int nk = (it < 63) ? 4 : 2;    // tail: only k 8064..8127 valid
            for (int ks = 0; ks < nk; ++ks) {
                int gg = ks * 4 + lg;
                int rowb = wc + lm;
                bf16x8 a  = *(const bf16x8*)(Ac + lm * 128 + ((gg ^ (lm & 7)) * 8));
                bf16x8 bv = *(const bf16x8*)(Bc + rowb * 128 + ((gg ^ (rowb & 7)) * 8));
                acc = __builtin_amdgcn_mfma_f32_16x16x32_bf16(a, bv, acc, 0, 0, 0);
            }
        }
        __syncthreads();
    }
    // C layout: col = lane&15, row = (lane>>4)*4 + reg.  Block = one n (=rt).
    if (w < 2) {
        #pragma unroll
        for (int r = 0; r < 4; ++r) {
            int a2 = lg * 4 + r;
            Xb[(size_t)(b * NN + rt) * XDIM + 2048 + a2 * DP + wc + lm] = f2bf(acc[r]);
        }
    }
}

// ---------------------------------------------------------------------------
// Kernel C: mlp layer1, 32x32 tiles, grid 512, XCD-swizzled, double-buffered,
// K-tile 128 (20 iters), fused bias+gelu -> Hb bf16.  LDS 32KB.
// ---------------------------------------------------------------------------
__global__ __launch_bounds__(256) void mlp1_k(
    const unsigned short* __restrict__ Xb,
    const unsigned short* __restrict__ Wt,
    const float* __restrict__ eb1, unsigned short* __restrict__ Hb)
{
    __shared__ unsigned short sm[16384];   // 32KB: 2 x (A 8KB + B 8KB)
    const int bid = blockIdx.x;
    const int xcd = bid & 7, idx = bid >> 3;      // idx 0..63
    const int rt = (xcd << 2) | (idx & 3);        // 0..31
    const int ct = idx >> 2;                      // 0..15
    const int rbase = rt * 32, nbase = ct * 32;
    const int t = threadIdx.x;
    const int w = t >> 6, lane = t & 63;
    const int lm = lane & 15, lg = lane >> 4;
    const int wr = (w & 1) * 16, wc = (w >> 1) * 16;
    const int srow = t >> 3, sg = t & 7;

    f32x4 acc = 0.f;

    const unsigned short* Arow = Xb + (size_t)(rbase + srow) * XDIM;
    const unsigned short* Brow = Wt + (size_t)(nbase + srow) * XDIM;

    bf16x8 rA0, rA1, rB0, rB1;

#define M1_LOAD(IT)  { int kn = (IT) * 128 + sg * 8;                         \
                       rA0 = *(const bf16x8*)(Arow + kn);                    \
                       rA1 = *(const bf16x8*)(Arow + kn + 64);               \
                       rB0 = *(const bf16x8*)(Brow + kn);                    \
                       rB1 = *(const bf16x8*)(Brow + kn + 64); }
#define M1_WRITE(BUF) { unsigned short* A_ = sm + (BUF) * 8192;              \
                        unsigned short* B_ = A_ + 4096;                      \
                        int g0 = sg ^ (srow & 7);                            \
                        *(bf16x8*)(A_ + srow * 128 + g0 * 8) = rA0;          \
                        *(bf16x8*)(A_ + srow * 128 + (g0 + 8) * 8) = rA1;    \
                        *(bf16x8*)(B_ + srow * 128 + g0 * 8) = rB0;          \
                        *(bf16x8*)(B_ + srow * 128 + (g0 + 8) * 8) = rB1; }

    M1_LOAD(0); M1_WRITE(0);
    __syncthreads();
    M1_LOAD(1);

    for (int it = 0; it < 20; ++it) {
        const int cur = it & 1;
        const unsigned short* Ac = sm + cur * 8192;
        const unsigned short* Bc = Ac + 4096;
        if (it + 1 < 20) M1_WRITE(cur ^ 1);
        if (it + 2 < 20) M1_LOAD(it + 2);
        #pragma unroll
        for (int ks = 0; ks < 4; ++ks) {
            int g = ks * 4 + lg;
            int r0 = wr + lm, r1 = wc + lm;
            bf16x8 a  = *(const bf16x8*)(Ac + r0 * 128 + ((g ^ (r0 & 7)) * 8));
            bf16x8 bv = *(const bf16x8*)(Bc + r1 * 128 + ((g ^ (r1 & 7)) * 8));
            acc = __builtin_amdgcn_mfma_f32_16x16x32_bf16(a, bv, acc, 0, 0, 0);
        }
        __syncthreads();
    }
    const int col = nbase + wc + lm;
    const float bb = eb1[col];
    #pragma unroll
    for (int r = 0; r < 4; ++r) {
        int row = rbase + wr + lg * 4 + r;
        Hb[(size_t)row * HH + col] = f2bf(gelu_f(acc[r] + bb));
    }
}

// ---------------------------------------------------------------------------
// Kernel D: mlp layer2, 32x32 tiles, grid 256, XCD-swizzled, double-buffered,
// K-tile 128 (4 iters), f32 out + eb2.  LDS 32KB.
// ---------------------------------------------------------------------------
__global__ __launch_bounds__(256) void mlp2_k(
    const unsigned short* __restrict__ Hb,
    const unsigned short* __restrict__ Wt,
    const float* __restrict__ eb2, float* __restrict__ out)
{
    __shared__ unsigned short sm[16384];
    const int bid = blockIdx.x;
    const int xcd = bid & 7, idx = bid >> 3;      // idx 0..31
    const int rt = (xcd << 2) | (idx & 3);        // 0..31
    const int ct = idx >> 2;                      // 0..7
    const int rbase = rt * 32, nbase = ct * 32;
    const int t = threadIdx.x;
    const int w = t >> 6, lane = t & 63;
    const int lm = lane & 15, lg = lane >> 4;
    const int wr = (w & 1) * 16, wc = (w >> 1) * 16;
    const int srow = t >> 3, sg = t & 7;

    f32x4 acc = 0.f;

    const unsigned short* Arow = Hb + (size_t)(rbase + srow) * HH;
    const unsigned short* Brow = Wt + (size_t)(nbase + srow) * HH;

    bf16x8 rA0, rA1, rB0, rB1;

#define M2_LOAD(IT)  { int kn = (IT) * 128 + sg * 8;                         \
                       rA0 = *(const bf16x8*)(Arow + kn);                    \
                       rA1 = *(const bf16x8*)(Arow + kn + 64);               \
                       rB0 = *(const bf16x8*)(Brow + kn);                    \
                       rB1 = *(const bf16x8*)(Brow + kn + 64); }
#define M2_WRITE(BUF) { unsigned short* A_ = sm + (BUF) * 8192;              \
                        unsigned short* B_ = A_ + 4096;                      \
                        int g0 = sg ^ (srow & 7);                            \
                        *(bf16x8*)(A_ + srow * 128 + g0 * 8) = rA0;          \
                        *(bf16x8*)(A_ + srow * 128 + (g0 + 8) * 8) = rA1;    \
                        *(bf16x8*)(B_ + srow * 128 + g0 * 8) = rB0;          \
                        *(bf16x8*)(B_ + srow * 128 + (g0 + 8) * 8) = rB1; }

    M2_LOAD(0); M2_WRITE(0);
    __syncthreads();
    M2_LOAD(1);

    for (int it = 0; it < 4; ++it) {
        const int cur = it & 1;
        const unsigned short* Ac = sm + cur * 8192;
        const unsigned short* Bc = Ac + 4096;
        if (it + 1 < 4) M2_WRITE(cur ^ 1);
        if (it + 2 < 4) M2_LOAD(it + 2);
        #pragma unroll
        for (int ks = 0; ks < 4; ++ks) {
            int g = ks * 4 + lg;
            int r0 = wr + lm, r1 = wc + lm;
            bf16x8 a  = *(const bf16x8*)(Ac + r0 * 128 + ((g ^ (r0 & 7)) * 8));
            bf16x8 bv = *(const bf16x8*)(Bc + r1 * 128 + ((g ^ (r1 & 7)) * 8));
            acc = __builtin_amdgcn_mfma_f32_16x16x32_bf16(a, bv, acc, 0, 0, 0);
        }
        __syncthreads();
    }
    const int col = nbase + wc + lm;
    const float bb = eb2[col];
    #pragma unroll
    for (int r = 0; r < 4; ++r) {
        int row = rbase + wr + lg * 4 + r;
        out[(size_t)row * EE + col] = acc[r] + bb;
    }
}

extern "C" void kernel_launch(void* const* d_in, const int* in_sizes, int n_in,
                              void* d_out, int out_size, void* d_ws, size_t ws_size,
                              hipStream_t stream) {
    const float* gr  = (const float*)d_in[0];
    const float* ga  = (const float*)d_in[1];
    const float* afv = (const float*)d_in[2];
    const float* cw1 = (const float*)d_in[3];
    const float* cb1 = (const float*)d_in[4];
    const float* cw2 = (const float*)d_in[5];
    const float* cb2 = (const float*)d_in[6];
    const float* ew1 = (const float*)d_in[7];
    const float* eb1 = (const float*)d_in[8];
    const float* ew2 = (const float*)d_in[9];
    const float* eb2 = (const float*)d_in[10];
    float* out = (float*)d_out;
    float* ws = (float*)d_ws;

    unsigned short* pairT  = (unsigned short*)(ws + WS_PAIRT);
    unsigned short* Xb     = (unsigned short*)(ws + WS_XB);
    unsigned short* ew1bT  = (unsigned short*)(ws + WS_EW1B);
    unsigned short* cw1T   = (unsigned short*)(ws + WS_CW1T);
    unsigned short* cw2T   = (unsigned short*)(ws + WS_CW2T);
    unsigned short* ew2bT  = (unsigned short*)(ws + WS_EW2B);
    unsigned short* Hb     = (unsigned short*)(ws + WS_HB);

    prep_k<<<dim3(20), dim3(256), 0, stream>>>(cw1, cw2, cw1T, cw2T);
    stage1_k<<<dim3(1016), dim3(256), 0, stream>>>(afv, cw1T, cb1, cw2T, cb2, pairT);
    gav_k<<<dim3(3008), dim3(256), 0, stream>>>(ga, pairT, Xb, gr, afv,
                                                ew1, ew1bT, ew2, ew2bT,
                                                out + (size_t)BB * NN * EE);
    mlp1_k<<<dim3(512), dim3(256), 0, stream>>>(Xb, ew1bT, eb1, Hb);
    mlp2_k<<<dim3(256), dim3(256), 0, stream>>>(Hb, ew2bT, eb2, out);
}